// Round 5
// baseline (931.046 us; speedup 1.0000x reference)
//
#include <hip/hip_runtime.h>
#include <hip/hip_bf16.h>
#include <math.h>

// bucket = 64 consecutive dst nodes. key packs (dlow<<17 | src), valid for n < 131072.
#define BSHIFT 6
#define BNODES 64
#define MAXB 1024  // max buckets supported by single-block scan (n <= 65536)

// ---------------- dtype detection: int64 vs int32 edge_index ----------------
__global__ void k_detect(const void* edges, long long nn, int* flag) {
    const long long* e64 = (const long long*)edges;
    int ok = 1;
    for (int i = 0; i < 8; ++i) {
        long long v = e64[i];
        if (v < 0 || v >= nn) { ok = 0; break; }
    }
    *flag = ok;
}

// ---------------- per-bucket edge counts (LDS hist -> few global atomics) ----------------
__global__ __launch_bounds__(512) void k_buckcount(const void* edges, const int* __restrict__ flag,
                                                   long long E, int nbuckets, int* totals) {
    __shared__ int cnt[MAXB];
    int t = threadIdx.x;
    for (int b = t; b < nbuckets; b += 512) cnt[b] = 0;
    __syncthreads();
    bool f64 = (*flag != 0);
    long long chunk = (E + gridDim.x - 1) / gridDim.x;
    long long e0 = (long long)blockIdx.x * chunk;
    long long e1 = e0 + chunk; if (e1 > E) e1 = E;
    for (long long e = e0 + t; e < e1; e += 512) {
        int d = f64 ? (int)((const long long*)edges)[E + e] : ((const int*)edges)[E + e];
        atomicAdd(&cnt[d >> BSHIFT], 1);
    }
    __syncthreads();
    for (int b = t; b < nbuckets; b += 512)
        if (cnt[b] > 0) atomicAdd(&totals[b], cnt[b]);
}

// ---------------- single-block scan: base = exclusive(totals), cursor = base ----------------
__global__ __launch_bounds__(1024) void k_scan(const int* __restrict__ totals, int nbuckets,
                                               int* base, int* cursor) {
    __shared__ int tmp[MAXB];
    int t = threadIdx.x;
    int v = (t < nbuckets) ? totals[t] : 0;
    tmp[t] = v;
    __syncthreads();
    for (int off = 1; off < MAXB; off <<= 1) {
        int a = (t >= off) ? tmp[t - off] : 0;
        __syncthreads();
        tmp[t] += a;
        __syncthreads();
    }
    if (t < nbuckets) {
        int ex = tmp[t] - v;
        base[t] = ex;
        cursor[t] = ex;
    }
}

// ---------------- bin edges into bucket-major key array ----------------
__global__ __launch_bounds__(512) void k_binscatter(const void* edges, const int* __restrict__ flag,
                                                    long long E, int nbuckets, int* cursor,
                                                    unsigned int* keys) {
    __shared__ int cnt[MAXB];
    __shared__ int base_l[MAXB];
    int t = threadIdx.x;
    for (int b = t; b < nbuckets; b += 512) cnt[b] = 0;
    __syncthreads();
    bool f64 = (*flag != 0);
    long long chunk = (E + gridDim.x - 1) / gridDim.x;
    long long e0 = (long long)blockIdx.x * chunk;
    long long e1 = e0 + chunk; if (e1 > E) e1 = E;
    // pass 1: local histogram
    for (long long e = e0 + t; e < e1; e += 512) {
        int d = f64 ? (int)((const long long*)edges)[E + e] : ((const int*)edges)[E + e];
        atomicAdd(&cnt[d >> BSHIFT], 1);
    }
    __syncthreads();
    // claim contiguous chunks per bucket
    for (int b = t; b < nbuckets; b += 512) {
        int c = cnt[b];
        base_l[b] = (c > 0) ? atomicAdd(&cursor[b], c) : 0;
        cnt[b] = 0;
    }
    __syncthreads();
    // pass 2: place keys
    for (long long e = e0 + t; e < e1; e += 512) {
        int s, d;
        if (f64) {
            const long long* ee = (const long long*)edges;
            s = (int)ee[e]; d = (int)ee[E + e];
        } else {
            const int* ee = (const int*)edges;
            s = ee[e]; d = ee[E + e];
        }
        int b = d >> BSHIFT;
        int pos = base_l[b] + atomicAdd(&cnt[b], 1);
        keys[pos] = (unsigned int)s | ((unsigned int)(d & (BNODES - 1)) << 17);
    }
}

// ---------------- per-bucket degree -> dinv ----------------
__global__ __launch_bounds__(256) void k_deg(const unsigned int* __restrict__ keys,
                                             const int* __restrict__ base,
                                             const int* __restrict__ totals,
                                             float* dinv, int n) {
    __shared__ int cnt[BNODES];
    int t = threadIdx.x;
    if (t < BNODES) cnt[t] = 0;
    __syncthreads();
    int bk = blockIdx.x;
    int st = base[bk], c = totals[bk];
    for (int i = t; i < c; i += 256) atomicAdd(&cnt[keys[st + i] >> 17], 1);
    __syncthreads();
    int node = bk * BNODES + t;
    if (t < BNODES && node < n) dinv[node] = rsqrtf((float)cnt[t] + 1.0f);
}

// ---------------- GEMM1: h1s[n,64] = dinv * (x[n,64] @ W1[64,64]) ----------------
__global__ __launch_bounds__(256) void k_gemm1(const float* __restrict__ x,
                                               const float* __restrict__ W,
                                               const float* __restrict__ dinv,
                                               float* __restrict__ h) {
    __shared__ float Ws[64][64];
    __shared__ float xs[16][64];
    int t = threadIdx.x;
    for (int i = t; i < 64 * 64; i += 256) Ws[i >> 6][i & 63] = W[i];
    long long row0 = (long long)blockIdx.x * 16;
    ((float4*)xs)[t] = ((const float4*)(x + row0 * 64))[t];
    __syncthreads();
    int r = t >> 4, c0 = (t & 15) * 4;
    float4 acc = {0.f, 0.f, 0.f, 0.f};
#pragma unroll
    for (int k = 0; k < 64; ++k) {
        float xv = xs[r][k];
        float4 wv = *((const float4*)&Ws[k][c0]);
        acc.x += xv * wv.x; acc.y += xv * wv.y;
        acc.z += xv * wv.z; acc.w += xv * wv.w;
    }
    float di = dinv[row0 + r];
    acc.x *= di; acc.y *= di; acc.z *= di; acc.w *= di;
    *((float4*)(h + (row0 + r) * 64 + c0)) = acc;
}

// ---------------- GEMM2: h2s[n,16] = dinv * (out1[n,64] @ W2[64,16]) ----------------
__global__ __launch_bounds__(256) void k_gemm2(const float* __restrict__ h,
                                               const float* __restrict__ W,
                                               const float* __restrict__ dinv,
                                               float* __restrict__ h2) {
    __shared__ float Ws[64 * 16];
    __shared__ float xs[16][64];
    int t = threadIdx.x;
    for (int i = t; i < 64 * 16; i += 256) Ws[i] = W[i];
    long long row0 = (long long)blockIdx.x * 16;
    ((float4*)xs)[t] = ((const float4*)(h + row0 * 64))[t];
    __syncthreads();
    int r = t >> 4, c = t & 15;
    float acc = 0.f;
#pragma unroll
    for (int k = 0; k < 64; ++k) acc += xs[r][k] * Ws[k * 16 + c];
    h2[(row0 + r) * 16 + c] = dinv[row0 + r] * acc;
}

// ---------------- bucket aggregation, 64 feats: LDS tile + ds_add ----------------
__global__ __launch_bounds__(256) void k_agg64(const unsigned int* __restrict__ keys,
                                               const int* __restrict__ base,
                                               const int* __restrict__ totals,
                                               const float* __restrict__ hs,
                                               const float* __restrict__ dinv,
                                               const float* __restrict__ b,
                                               float* __restrict__ out, int n) {
    __shared__ float tile[BNODES * 64];
    int t = threadIdx.x;
    int bk = blockIdx.x;
    int node0 = bk * BNODES;
    int nrows = n - node0; if (nrows > BNODES) nrows = BNODES;
    // init tile with self-loop term (rows contiguous = hs rows)
    for (int i = t; i < nrows * 16; i += 256)
        ((float4*)tile)[i] = ((const float4*)(hs + (long long)node0 * 64))[i];
    __syncthreads();
    int wid = t >> 6, lane = t & 63;
    int st = base[bk], c = totals[bk];
    int i = wid;
    // unroll x2 for two outstanding gathers
    for (; i + 4 < c; i += 8) {
        unsigned int k0 = keys[st + i];
        unsigned int k1 = keys[st + i + 4];
        float v0 = hs[(long long)(k0 & 0x1FFFF) * 64 + lane];
        float v1 = hs[(long long)(k1 & 0x1FFFF) * 64 + lane];
        unsafeAtomicAdd(&tile[(k0 >> 17) * 64 + lane], v0);
        unsafeAtomicAdd(&tile[(k1 >> 17) * 64 + lane], v1);
    }
    for (; i < c; i += 4) {
        unsigned int k0 = keys[st + i];
        float v0 = hs[(long long)(k0 & 0x1FFFF) * 64 + lane];
        unsafeAtomicAdd(&tile[(k0 >> 17) * 64 + lane], v0);
    }
    __syncthreads();
    // epilogue: out = relu(dinv*acc + b)
    for (int idx = t; idx < nrows * 64; idx += 256) {
        int r = idx >> 6, f = idx & 63;
        float v = dinv[node0 + r] * tile[idx] + b[f];
        out[(long long)node0 * 64 + idx] = fmaxf(v, 0.f);
    }
}

// ---------------- bucket aggregation, 16 feats + fused log_softmax ----------------
__global__ __launch_bounds__(256) void k_agg16(const unsigned int* __restrict__ keys,
                                               const int* __restrict__ base,
                                               const int* __restrict__ totals,
                                               const float* __restrict__ hs,
                                               const float* __restrict__ dinv,
                                               const float* __restrict__ b,
                                               float* __restrict__ out, int n) {
    __shared__ float tile[BNODES * 16];
    int t = threadIdx.x;
    int bk = blockIdx.x;
    int node0 = bk * BNODES;
    int nrows = n - node0; if (nrows > BNODES) nrows = BNODES;
    for (int i = t; i < nrows * 4; i += 256)
        ((float4*)tile)[i] = ((const float4*)(hs + (long long)node0 * 16))[i];
    __syncthreads();
    int grp = t >> 4, f = t & 15;  // 16 groups of 16 lanes
    int st = base[bk], c = totals[bk];
    int i = grp;
    for (; i + 16 < c; i += 32) {
        unsigned int k0 = keys[st + i];
        unsigned int k1 = keys[st + i + 16];
        float v0 = hs[(long long)(k0 & 0x1FFFF) * 16 + f];
        float v1 = hs[(long long)(k1 & 0x1FFFF) * 16 + f];
        unsafeAtomicAdd(&tile[(k0 >> 17) * 16 + f], v0);
        unsafeAtomicAdd(&tile[(k1 >> 17) * 16 + f], v1);
    }
    for (; i < c; i += 16) {
        unsigned int k0 = keys[st + i];
        float v0 = hs[(long long)(k0 & 0x1FFFF) * 16 + f];
        unsafeAtomicAdd(&tile[(k0 >> 17) * 16 + f], v0);
    }
    __syncthreads();
    for (int r = t >> 4; r < nrows; r += 16) {
        float v = dinv[node0 + r] * tile[r * 16 + f] + b[f];
        float m = v;
#pragma unroll
        for (int o = 8; o >= 1; o >>= 1) m = fmaxf(m, __shfl_xor(m, o, 16));
        float ex = __expf(v - m);
#pragma unroll
        for (int o = 8; o >= 1; o >>= 1) ex += __shfl_xor(ex, o, 16);
        out[(long long)(node0 + r) * 16 + f] = (v - m) - __logf(ex);
    }
}

extern "C" void kernel_launch(void* const* d_in, const int* in_sizes, int n_in,
                              void* d_out, int out_size, void* d_ws, size_t ws_size,
                              hipStream_t stream) {
    const float* x  = (const float*)d_in[0];
    const void*  ei = d_in[1];
    const float* W1 = (const float*)d_in[2];
    const float* b1 = (const float*)d_in[3];
    const float* W2 = (const float*)d_in[4];
    const float* b2 = (const float*)d_in[5];

    long long dh  = in_sizes[3];                 // 64
    long long din = in_sizes[2] / dh;            // 64
    long long n   = in_sizes[0] / din;           // 50000
    long long E   = (long long)in_sizes[1] / 2;  // 1.6M
    int nbuckets  = (int)((n + BNODES - 1) >> BSHIFT);  // 782

    char* ws = (char*)d_ws;
    auto alloc = [&](size_t bytes) { void* p = ws; ws += (bytes + 255) & ~255ULL; return p; };
    int*   flag   = (int*)alloc(4);
    int*   totals = (int*)alloc(nbuckets * 4);
    int*   base   = (int*)alloc(nbuckets * 4);
    int*   cursor = (int*)alloc(nbuckets * 4);
    float* dinv   = (float*)alloc(n * 4);
    unsigned int* keys = (unsigned int*)alloc(E * 4);
    float* h1s    = (float*)alloc(n * 64 * 4);
    float* out1   = (float*)alloc(n * 64 * 4);
    float* h2s    = h1s;  // h1s dead after k_agg64

    float* out = (float*)d_out;

    hipMemsetAsync(totals, 0, (size_t)nbuckets * 4, stream);

    k_detect<<<1, 1, 0, stream>>>(ei, n, flag);
    k_buckcount<<<128, 512, 0, stream>>>(ei, flag, E, nbuckets, totals);
    k_scan<<<1, 1024, 0, stream>>>(totals, nbuckets, base, cursor);
    k_binscatter<<<128, 512, 0, stream>>>(ei, flag, E, nbuckets, cursor, keys);
    k_deg<<<nbuckets, 256, 0, stream>>>(keys, base, totals, dinv, (int)n);

    // layer 1
    k_gemm1<<<(int)(n / 16), 256, 0, stream>>>(x, W1, dinv, h1s);
    k_agg64<<<nbuckets, 256, 0, stream>>>(keys, base, totals, h1s, dinv, b1, out1, (int)n);

    // layer 2
    k_gemm2<<<(int)(n / 16), 256, 0, stream>>>(out1, W2, dinv, h2s);
    k_agg16<<<nbuckets, 256, 0, stream>>>(keys, base, totals, h2s, dinv, b2, out, (int)n);
}

// Round 6
// 159.448 us; speedup vs baseline: 5.8392x; 5.8392x over previous
//
#include <hip/hip_runtime.h>
#include <hip/hip_bf16.h>
#include <math.h>

// bucket = 64 consecutive dst nodes. key packs (dlow<<17 | src), valid for n < 131072.
#define BSHIFT 6
#define BNODES 64
#define MAXB 1024   // max buckets supported by single-block scan (n <= 65536)
#define SORTCAP 4096

// ---------------- dtype detection: int64 vs int32 edge_index ----------------
__global__ void k_detect(const void* edges, long long nn, int* flag) {
    const long long* e64 = (const long long*)edges;
    int ok = 1;
    for (int i = 0; i < 8; ++i) {
        long long v = e64[i];
        if (v < 0 || v >= nn) { ok = 0; break; }
    }
    *flag = ok;
}

// ---------------- per-bucket edge counts (LDS hist -> few global atomics) ----------------
__global__ __launch_bounds__(512) void k_buckcount(const void* edges, const int* __restrict__ flag,
                                                   long long E, int nbuckets, int* totals) {
    __shared__ int cnt[MAXB];
    int t = threadIdx.x;
    for (int b = t; b < nbuckets; b += 512) cnt[b] = 0;
    __syncthreads();
    bool f64 = (*flag != 0);
    long long chunk = (E + gridDim.x - 1) / gridDim.x;
    long long e0 = (long long)blockIdx.x * chunk;
    long long e1 = e0 + chunk; if (e1 > E) e1 = E;
    for (long long e = e0 + t; e < e1; e += 512) {
        int d = f64 ? (int)((const long long*)edges)[E + e] : ((const int*)edges)[E + e];
        atomicAdd(&cnt[d >> BSHIFT], 1);
    }
    __syncthreads();
    for (int b = t; b < nbuckets; b += 512)
        if (cnt[b] > 0) atomicAdd(&totals[b], cnt[b]);
}

// ---------------- single-block scan: base = exclusive(totals), cursor = base ----------------
__global__ __launch_bounds__(1024) void k_scan(const int* __restrict__ totals, int nbuckets,
                                               int* base, int* cursor) {
    __shared__ int tmp[MAXB];
    int t = threadIdx.x;
    int v = (t < nbuckets) ? totals[t] : 0;
    tmp[t] = v;
    __syncthreads();
    for (int off = 1; off < MAXB; off <<= 1) {
        int a = (t >= off) ? tmp[t - off] : 0;
        __syncthreads();
        tmp[t] += a;
        __syncthreads();
    }
    if (t < nbuckets) {
        int ex = tmp[t] - v;
        base[t] = ex;
        cursor[t] = ex;
    }
}

// ---------------- bin edges into bucket-major key array ----------------
__global__ __launch_bounds__(512) void k_binscatter(const void* edges, const int* __restrict__ flag,
                                                    long long E, int nbuckets, int* cursor,
                                                    unsigned int* keys) {
    __shared__ int cnt[MAXB];
    __shared__ int base_l[MAXB];
    int t = threadIdx.x;
    for (int b = t; b < nbuckets; b += 512) cnt[b] = 0;
    __syncthreads();
    bool f64 = (*flag != 0);
    long long chunk = (E + gridDim.x - 1) / gridDim.x;
    long long e0 = (long long)blockIdx.x * chunk;
    long long e1 = e0 + chunk; if (e1 > E) e1 = E;
    // pass 1: local histogram
    for (long long e = e0 + t; e < e1; e += 512) {
        int d = f64 ? (int)((const long long*)edges)[E + e] : ((const int*)edges)[E + e];
        atomicAdd(&cnt[d >> BSHIFT], 1);
    }
    __syncthreads();
    // claim contiguous chunks per bucket
    for (int b = t; b < nbuckets; b += 512) {
        int c = cnt[b];
        base_l[b] = (c > 0) ? atomicAdd(&cursor[b], c) : 0;
        cnt[b] = 0;
    }
    __syncthreads();
    // pass 2: place keys
    for (long long e = e0 + t; e < e1; e += 512) {
        int s, d;
        if (f64) {
            const long long* ee = (const long long*)edges;
            s = (int)ee[e]; d = (int)ee[E + e];
        } else {
            const int* ee = (const int*)edges;
            s = ee[e]; d = ee[E + e];
        }
        int b = d >> BSHIFT;
        int pos = base_l[b] + atomicAdd(&cnt[b], 1);
        keys[pos] = (unsigned int)s | ((unsigned int)(d & (BNODES - 1)) << 17);
    }
}

// -------- per-bucket LDS counting sort -> node-exact CSR; fuses deg/dinv --------
// After this kernel, keys[rowstart[d] .. rowstart[d]+counts[d]) holds the src
// indices (low 17 bits) of node d's in-edges.
__global__ __launch_bounds__(256) void k_sortdeg(unsigned int* keys,
                                                 const int* __restrict__ base,
                                                 const int* __restrict__ totals,
                                                 int* rowstart, int* counts,
                                                 float* dinv, int n,
                                                 unsigned int* scratch) {
    __shared__ unsigned int kbuf[SORTCAP];
    __shared__ int hist[BNODES];
    __shared__ int cur[BNODES];
    int t = threadIdx.x;
    int bk = blockIdx.x;
    int st = base[bk], c = totals[bk];
    if (t < BNODES) hist[t] = 0;
    __syncthreads();
    bool fits = (c <= SORTCAP);
    if (fits) {
        for (int i = t; i < c; i += 256) {
            unsigned int k = keys[st + i];
            kbuf[i] = k;
            atomicAdd(&hist[k >> 17], 1);
        }
    } else {  // statistically never for random edges; correct fallback via global scratch
        for (int i = t; i < c; i += 256) {
            unsigned int k = keys[st + i];
            scratch[st + i] = k;
            atomicAdd(&hist[k >> 17], 1);
        }
    }
    __syncthreads();
    if (t < 64) {  // wave 0: scan 64 counters
        int v = hist[t];
        int incl = v;
        for (int o = 1; o < 64; o <<= 1) {
            int other = __shfl_up(incl, o, 64);
            if (t >= o) incl += other;
        }
        int ex = incl - v;
        cur[t] = ex;
        int node = bk * BNODES + t;
        if (node < n) {
            rowstart[node] = st + ex;
            counts[node] = v;
            dinv[node] = rsqrtf((float)v + 1.0f);
        }
    }
    __syncthreads();
    if (fits) {
        for (int i = t; i < c; i += 256) {
            unsigned int k = kbuf[i];
            int pos = atomicAdd(&cur[k >> 17], 1);
            keys[st + pos] = k & 0x1FFFFu;
        }
    } else {
        for (int i = t; i < c; i += 256) {
            unsigned int k = scratch[st + i];
            int pos = atomicAdd(&cur[k >> 17], 1);
            keys[st + pos] = k & 0x1FFFFu;
        }
    }
}

// ---------------- GEMM1: h1s[n,64] = dinv * (x[n,64] @ W1[64,64]) ----------------
__global__ __launch_bounds__(256) void k_gemm1(const float* __restrict__ x,
                                               const float* __restrict__ W,
                                               const float* __restrict__ dinv,
                                               float* __restrict__ h) {
    __shared__ float Ws[64][64];
    __shared__ float xs[16][64];
    int t = threadIdx.x;
    for (int i = t; i < 64 * 64; i += 256) Ws[i >> 6][i & 63] = W[i];
    long long row0 = (long long)blockIdx.x * 16;
    ((float4*)xs)[t] = ((const float4*)(x + row0 * 64))[t];
    __syncthreads();
    int r = t >> 4, c0 = (t & 15) * 4;
    float4 acc = {0.f, 0.f, 0.f, 0.f};
#pragma unroll
    for (int k = 0; k < 64; ++k) {
        float xv = xs[r][k];
        float4 wv = *((const float4*)&Ws[k][c0]);
        acc.x += xv * wv.x; acc.y += xv * wv.y;
        acc.z += xv * wv.z; acc.w += xv * wv.w;
    }
    float di = dinv[row0 + r];
    acc.x *= di; acc.y *= di; acc.z *= di; acc.w *= di;
    *((float4*)(h + (row0 + r) * 64 + c0)) = acc;
}

// ---------------- GEMM2: h2s[n,16] = dinv * (out1[n,64] @ W2[64,16]) ----------------
__global__ __launch_bounds__(256) void k_gemm2(const float* __restrict__ h,
                                               const float* __restrict__ W,
                                               const float* __restrict__ dinv,
                                               float* __restrict__ h2) {
    __shared__ float Ws[64 * 16];
    __shared__ float xs[16][64];
    int t = threadIdx.x;
    for (int i = t; i < 64 * 16; i += 256) Ws[i] = W[i];
    long long row0 = (long long)blockIdx.x * 16;
    ((float4*)xs)[t] = ((const float4*)(h + row0 * 64))[t];
    __syncthreads();
    int r = t >> 4, c = t & 15;
    float acc = 0.f;
#pragma unroll
    for (int k = 0; k < 64; ++k) acc += xs[r][k] * Ws[k * 16 + c];
    h2[(row0 + r) * 16 + c] = dinv[row0 + r] * acc;
}

// ------- CSR aggregation, 64 feats: wave per node, lane = feature, 4-wide MLP -------
__global__ __launch_bounds__(256) void k_agg64(const int* __restrict__ rowstart,
                                               const int* __restrict__ counts,
                                               const unsigned int* __restrict__ srcs,
                                               const float* __restrict__ hs,
                                               const float* __restrict__ dinv,
                                               const float* __restrict__ b,
                                               float* __restrict__ out, int n) {
    int d = (blockIdx.x * 256 + threadIdx.x) >> 6;
    if (d >= n) return;
    int f = threadIdx.x & 63;
    long long rb = (long long)d * 64;
    float acc = hs[rb + f];  // self-loop
    int start = rowstart[d];
    int cnt = counts[d];
    int k = 0;
    for (; k + 4 <= cnt; k += 4) {
        unsigned int s0 = srcs[start + k];
        unsigned int s1 = srcs[start + k + 1];
        unsigned int s2 = srcs[start + k + 2];
        unsigned int s3 = srcs[start + k + 3];
        float v0 = hs[(long long)s0 * 64 + f];
        float v1 = hs[(long long)s1 * 64 + f];
        float v2 = hs[(long long)s2 * 64 + f];
        float v3 = hs[(long long)s3 * 64 + f];
        acc += v0; acc += v1; acc += v2; acc += v3;
    }
    for (; k < cnt; ++k) acc += hs[(long long)srcs[start + k] * 64 + f];
    float v = dinv[d] * acc + b[f];
    out[rb + f] = fmaxf(v, 0.f);
}

// ------- CSR aggregation, 16 feats + fused log_softmax: 16-lane group per node -------
__global__ __launch_bounds__(256) void k_agg16(const int* __restrict__ rowstart,
                                               const int* __restrict__ counts,
                                               const unsigned int* __restrict__ srcs,
                                               const float* __restrict__ hs,
                                               const float* __restrict__ dinv,
                                               const float* __restrict__ b,
                                               float* __restrict__ out, int n) {
    int g = (blockIdx.x * 256 + threadIdx.x) >> 4;
    if (g >= n) return;
    int f = threadIdx.x & 15;
    long long rb = (long long)g * 16;
    float acc = hs[rb + f];
    int start = rowstart[g];
    int cnt = counts[g];
    int k = 0;
    for (; k + 4 <= cnt; k += 4) {
        unsigned int s0 = srcs[start + k];
        unsigned int s1 = srcs[start + k + 1];
        unsigned int s2 = srcs[start + k + 2];
        unsigned int s3 = srcs[start + k + 3];
        float v0 = hs[(long long)s0 * 16 + f];
        float v1 = hs[(long long)s1 * 16 + f];
        float v2 = hs[(long long)s2 * 16 + f];
        float v3 = hs[(long long)s3 * 16 + f];
        acc += v0; acc += v1; acc += v2; acc += v3;
    }
    for (; k < cnt; ++k) acc += hs[(long long)srcs[start + k] * 16 + f];
    float v = dinv[g] * acc + b[f];
    float m = v;
#pragma unroll
    for (int o = 8; o >= 1; o >>= 1) m = fmaxf(m, __shfl_xor(m, o, 16));
    float ex = __expf(v - m);
#pragma unroll
    for (int o = 8; o >= 1; o >>= 1) ex += __shfl_xor(ex, o, 16);
    out[rb + f] = (v - m) - __logf(ex);
}

extern "C" void kernel_launch(void* const* d_in, const int* in_sizes, int n_in,
                              void* d_out, int out_size, void* d_ws, size_t ws_size,
                              hipStream_t stream) {
    const float* x  = (const float*)d_in[0];
    const void*  ei = d_in[1];
    const float* W1 = (const float*)d_in[2];
    const float* b1 = (const float*)d_in[3];
    const float* W2 = (const float*)d_in[4];
    const float* b2 = (const float*)d_in[5];

    long long dh  = in_sizes[3];                 // 64
    long long din = in_sizes[2] / dh;            // 64
    long long n   = in_sizes[0] / din;           // 50000
    long long E   = (long long)in_sizes[1] / 2;  // 1.6M
    int nbuckets  = (int)((n + BNODES - 1) >> BSHIFT);  // 782

    char* ws = (char*)d_ws;
    auto alloc = [&](size_t bytes) { void* p = ws; ws += (bytes + 255) & ~255ULL; return p; };
    int*   flag     = (int*)alloc(4);
    int*   totals   = (int*)alloc(nbuckets * 4);
    int*   base     = (int*)alloc(nbuckets * 4);
    int*   cursor   = (int*)alloc(nbuckets * 4);
    int*   rowstart = (int*)alloc(n * 4);
    int*   counts   = (int*)alloc(n * 4);
    float* dinv     = (float*)alloc(n * 4);
    unsigned int* keys = (unsigned int*)alloc(E * 4);
    float* h1s      = (float*)alloc(n * 64 * 4);
    float* out1     = (float*)alloc(n * 64 * 4);
    float* h2s      = h1s;  // h1s dead after k_agg64
    // out1 is written only by gemm1-epoch kernels; before gemm1 runs, its space
    // doubles as the (statistically never used) big-bucket sort scratch.
    unsigned int* sort_scratch = (unsigned int*)out1;

    float* out = (float*)d_out;

    hipMemsetAsync(totals, 0, (size_t)nbuckets * 4, stream);

    k_detect<<<1, 1, 0, stream>>>(ei, n, flag);
    k_buckcount<<<256, 512, 0, stream>>>(ei, flag, E, nbuckets, totals);
    k_scan<<<1, 1024, 0, stream>>>(totals, nbuckets, base, cursor);
    k_binscatter<<<256, 512, 0, stream>>>(ei, flag, E, nbuckets, cursor, keys);
    k_sortdeg<<<nbuckets, 256, 0, stream>>>(keys, base, totals, rowstart, counts,
                                            dinv, (int)n, sort_scratch);

    // layer 1
    k_gemm1<<<(int)(n / 16), 256, 0, stream>>>(x, W1, dinv, h1s);
    k_agg64<<<(int)((n * 64 + 255) / 256), 256, 0, stream>>>(
        rowstart, counts, keys, h1s, dinv, b1, out1, (int)n);

    // layer 2
    k_gemm2<<<(int)(n / 16), 256, 0, stream>>>(out1, W2, dinv, h2s);
    k_agg16<<<(int)((n * 16 + 255) / 256), 256, 0, stream>>>(
        rowstart, counts, keys, h2s, dinv, b2, out, (int)n);
}

// Round 7
// 144.820 us; speedup vs baseline: 6.4290x; 1.1010x over previous
//
#include <hip/hip_runtime.h>
#include <hip/hip_bf16.h>
#include <math.h>

// bucket = 64 consecutive dst nodes. key packs (dlow<<17 | src), valid for n < 131072.
#define BSHIFT 6
#define BNODES 64
#define MAXB 1024   // max buckets supported by single-block scan (n <= 65536)
#define SORTCAP 4096
#define TILE 16     // edges cached in registers per thread in k_binscatter

// ---------------- dtype detection: int64 vs int32 edge_index ----------------
__global__ void k_detect(const void* edges, long long nn, int* flag) {
    const long long* e64 = (const long long*)edges;
    int ok = 1;
    for (int i = 0; i < 8; ++i) {
        long long v = e64[i];
        if (v < 0 || v >= nn) { ok = 0; break; }
    }
    *flag = ok;
}

// ---------------- per-bucket edge counts (LDS hist -> few global atomics) ----------------
__global__ __launch_bounds__(512) void k_buckcount(const void* edges, const int* __restrict__ flag,
                                                   long long E, int nbuckets, int* totals) {
    __shared__ int cnt[MAXB];
    int t = threadIdx.x;
    for (int b = t; b < nbuckets; b += 512) cnt[b] = 0;
    __syncthreads();
    bool f64 = (*flag != 0);
    long long chunk = (E + gridDim.x - 1) / gridDim.x;
    long long e0 = (long long)blockIdx.x * chunk;
    long long e1 = e0 + chunk; if (e1 > E) e1 = E;
    for (long long e = e0 + t; e < e1; e += 512) {
        int d = f64 ? (int)((const long long*)edges)[E + e] : ((const int*)edges)[E + e];
        atomicAdd(&cnt[d >> BSHIFT], 1);
    }
    __syncthreads();
    for (int b = t; b < nbuckets; b += 512)
        if (cnt[b] > 0) atomicAdd(&totals[b], cnt[b]);
}

// ---------------- single-block scan: base = exclusive(totals), cursor = base ----------------
__global__ __launch_bounds__(1024) void k_scan(const int* __restrict__ totals, int nbuckets,
                                               int* base, int* cursor) {
    __shared__ int tmp[MAXB];
    int t = threadIdx.x;
    int v = (t < nbuckets) ? totals[t] : 0;
    tmp[t] = v;
    __syncthreads();
    for (int off = 1; off < MAXB; off <<= 1) {
        int a = (t >= off) ? tmp[t - off] : 0;
        __syncthreads();
        tmp[t] += a;
        __syncthreads();
    }
    if (t < nbuckets) {
        int ex = tmp[t] - v;
        base[t] = ex;
        cursor[t] = ex;
    }
}

// ------- bin edges into bucket-major key array (single edge read, reg-cached) -------
__global__ __launch_bounds__(512) void k_binscatter(const void* edges, const int* __restrict__ flag,
                                                    long long E, int nbuckets, int* cursor,
                                                    unsigned int* keys) {
    __shared__ int cnt[MAXB];
    __shared__ int base_l[MAXB];
    int t = threadIdx.x;
    bool f64 = (*flag != 0);
    long long chunk = (E + gridDim.x - 1) / gridDim.x;
    long long e0 = (long long)blockIdx.x * chunk;
    long long e1 = e0 + chunk; if (e1 > E) e1 = E;
    for (long long tile0 = e0; tile0 < e1; tile0 += (long long)512 * TILE) {
        for (int b = t; b < nbuckets; b += 512) cnt[b] = 0;
        __syncthreads();
        int ss[TILE], dd[TILE];
        // pass 1: load once into registers + LDS histogram
#pragma unroll
        for (int j = 0; j < TILE; ++j) {
            long long e = tile0 + (long long)j * 512 + t;
            int s = 0, d = -1;
            if (e < e1) {
                if (f64) {
                    const long long* ee = (const long long*)edges;
                    s = (int)ee[e]; d = (int)ee[E + e];
                } else {
                    const int* ee = (const int*)edges;
                    s = ee[e]; d = ee[E + e];
                }
                atomicAdd(&cnt[d >> BSHIFT], 1);
            }
            ss[j] = s; dd[j] = d;
        }
        __syncthreads();
        // claim contiguous chunks per bucket
        for (int b = t; b < nbuckets; b += 512) {
            int c = cnt[b];
            base_l[b] = (c > 0) ? atomicAdd(&cursor[b], c) : 0;
            cnt[b] = 0;
        }
        __syncthreads();
        // pass 2: place keys from registers
#pragma unroll
        for (int j = 0; j < TILE; ++j) {
            int d = dd[j];
            if (d >= 0) {
                int b = d >> BSHIFT;
                int pos = base_l[b] + atomicAdd(&cnt[b], 1);
                keys[pos] = (unsigned int)ss[j] | ((unsigned int)(d & (BNODES - 1)) << 17);
            }
        }
        __syncthreads();
    }
}

// -------- per-bucket LDS counting sort -> node-exact CSR; fuses deg/dinv --------
__global__ __launch_bounds__(256) void k_sortdeg(unsigned int* keys,
                                                 const int* __restrict__ base,
                                                 const int* __restrict__ totals,
                                                 int* rowstart, int* counts,
                                                 float* dinv, int n,
                                                 unsigned int* scratch) {
    __shared__ unsigned int kbuf[SORTCAP];
    __shared__ int hist[BNODES];
    __shared__ int cur[BNODES];
    int t = threadIdx.x;
    int bk = blockIdx.x;
    int st = base[bk], c = totals[bk];
    if (t < BNODES) hist[t] = 0;
    __syncthreads();
    bool fits = (c <= SORTCAP);
    if (fits) {
        for (int i = t; i < c; i += 256) {
            unsigned int k = keys[st + i];
            kbuf[i] = k;
            atomicAdd(&hist[k >> 17], 1);
        }
    } else {  // statistically never for random edges; correct fallback via global scratch
        for (int i = t; i < c; i += 256) {
            unsigned int k = keys[st + i];
            scratch[st + i] = k;
            atomicAdd(&hist[k >> 17], 1);
        }
    }
    __syncthreads();
    if (t < 64) {  // wave 0: scan 64 counters
        int v = hist[t];
        int incl = v;
        for (int o = 1; o < 64; o <<= 1) {
            int other = __shfl_up(incl, o, 64);
            if (t >= o) incl += other;
        }
        int ex = incl - v;
        cur[t] = ex;
        int node = bk * BNODES + t;
        if (node < n) {
            rowstart[node] = st + ex;
            counts[node] = v;
            dinv[node] = rsqrtf((float)v + 1.0f);
        }
    }
    __syncthreads();
    if (fits) {
        for (int i = t; i < c; i += 256) {
            unsigned int k = kbuf[i];
            int pos = atomicAdd(&cur[k >> 17], 1);
            keys[st + pos] = k & 0x1FFFFu;
        }
    } else {
        for (int i = t; i < c; i += 256) {
            unsigned int k = scratch[st + i];
            int pos = atomicAdd(&cur[k >> 17], 1);
            keys[st + pos] = k & 0x1FFFFu;
        }
    }
}

// -------- GEMM1: h1b[n,64](bf16) = dinv * (x[n,64] @ W1[64,64]) --------
__global__ __launch_bounds__(256) void k_gemm1(const float* __restrict__ x,
                                               const float* __restrict__ W,
                                               const float* __restrict__ dinv,
                                               unsigned short* __restrict__ h) {
    __shared__ float Ws[64][64];
    __shared__ float xs[16][64];
    int t = threadIdx.x;
    for (int i = t; i < 64 * 64; i += 256) Ws[i >> 6][i & 63] = W[i];
    long long row0 = (long long)blockIdx.x * 16;
    ((float4*)xs)[t] = ((const float4*)(x + row0 * 64))[t];
    __syncthreads();
    int r = t >> 4, c0 = (t & 15) * 4;
    float4 acc = {0.f, 0.f, 0.f, 0.f};
#pragma unroll
    for (int k = 0; k < 64; ++k) {
        float xv = xs[r][k];
        float4 wv = *((const float4*)&Ws[k][c0]);
        acc.x += xv * wv.x; acc.y += xv * wv.y;
        acc.z += xv * wv.z; acc.w += xv * wv.w;
    }
    float di = dinv[row0 + r];
    __hip_bfloat16 q0 = __float2bfloat16(di * acc.x);
    __hip_bfloat16 q1 = __float2bfloat16(di * acc.y);
    __hip_bfloat16 q2 = __float2bfloat16(di * acc.z);
    __hip_bfloat16 q3 = __float2bfloat16(di * acc.w);
    ushort4 pk;
    pk.x = *reinterpret_cast<unsigned short*>(&q0);
    pk.y = *reinterpret_cast<unsigned short*>(&q1);
    pk.z = *reinterpret_cast<unsigned short*>(&q2);
    pk.w = *reinterpret_cast<unsigned short*>(&q3);
    *((ushort4*)(h + (row0 + r) * 64 + c0)) = pk;
}

// ---------------- GEMM2: h2s[n,16] = dinv * (out1[n,64] @ W2[64,16]) ----------------
__global__ __launch_bounds__(256) void k_gemm2(const float* __restrict__ h,
                                               const float* __restrict__ W,
                                               const float* __restrict__ dinv,
                                               float* __restrict__ h2) {
    __shared__ float Ws[64 * 16];
    __shared__ float xs[16][64];
    int t = threadIdx.x;
    for (int i = t; i < 64 * 16; i += 256) Ws[i] = W[i];
    long long row0 = (long long)blockIdx.x * 16;
    ((float4*)xs)[t] = ((const float4*)(h + row0 * 64))[t];
    __syncthreads();
    int r = t >> 4, c = t & 15;
    float acc = 0.f;
#pragma unroll
    for (int k = 0; k < 64; ++k) acc += xs[r][k] * Ws[k * 16 + c];
    h2[(row0 + r) * 16 + c] = dinv[row0 + r] * acc;
}

__device__ __forceinline__ float bf16dec(unsigned short u) {
    return __uint_as_float(((unsigned int)u) << 16);
}

// ------- CSR aggregation, 64 feats (bf16 h): wave per node, lane = feature -------
__global__ __launch_bounds__(256) void k_agg64(const int* __restrict__ rowstart,
                                               const int* __restrict__ counts,
                                               const unsigned int* __restrict__ srcs,
                                               const unsigned short* __restrict__ hb,
                                               const float* __restrict__ dinv,
                                               const float* __restrict__ b,
                                               float* __restrict__ out, int n) {
    int d = (blockIdx.x * 256 + threadIdx.x) >> 6;
    if (d >= n) return;
    int f = threadIdx.x & 63;
    long long rb = (long long)d * 64;
    float acc = bf16dec(hb[rb + f]);  // self-loop
    int start = rowstart[d];
    int cnt = counts[d];
    int k = 0;
    for (; k + 8 <= cnt; k += 8) {
        unsigned int s0 = srcs[start + k];
        unsigned int s1 = srcs[start + k + 1];
        unsigned int s2 = srcs[start + k + 2];
        unsigned int s3 = srcs[start + k + 3];
        unsigned int s4 = srcs[start + k + 4];
        unsigned int s5 = srcs[start + k + 5];
        unsigned int s6 = srcs[start + k + 6];
        unsigned int s7 = srcs[start + k + 7];
        unsigned short u0 = hb[(long long)s0 * 64 + f];
        unsigned short u1 = hb[(long long)s1 * 64 + f];
        unsigned short u2 = hb[(long long)s2 * 64 + f];
        unsigned short u3 = hb[(long long)s3 * 64 + f];
        unsigned short u4 = hb[(long long)s4 * 64 + f];
        unsigned short u5 = hb[(long long)s5 * 64 + f];
        unsigned short u6 = hb[(long long)s6 * 64 + f];
        unsigned short u7 = hb[(long long)s7 * 64 + f];
        acc += bf16dec(u0); acc += bf16dec(u1); acc += bf16dec(u2); acc += bf16dec(u3);
        acc += bf16dec(u4); acc += bf16dec(u5); acc += bf16dec(u6); acc += bf16dec(u7);
    }
    for (; k < cnt; ++k) acc += bf16dec(hb[(long long)srcs[start + k] * 64 + f]);
    float v = dinv[d] * acc + b[f];
    out[rb + f] = fmaxf(v, 0.f);
}

// ------- CSR aggregation, 16 feats + fused log_softmax: 16-lane group per node -------
__global__ __launch_bounds__(256) void k_agg16(const int* __restrict__ rowstart,
                                               const int* __restrict__ counts,
                                               const unsigned int* __restrict__ srcs,
                                               const float* __restrict__ hs,
                                               const float* __restrict__ dinv,
                                               const float* __restrict__ b,
                                               float* __restrict__ out, int n) {
    int g = (blockIdx.x * 256 + threadIdx.x) >> 4;
    if (g >= n) return;
    int f = threadIdx.x & 15;
    long long rb = (long long)g * 16;
    float acc = hs[rb + f];
    int start = rowstart[g];
    int cnt = counts[g];
    int k = 0;
    for (; k + 4 <= cnt; k += 4) {
        unsigned int s0 = srcs[start + k];
        unsigned int s1 = srcs[start + k + 1];
        unsigned int s2 = srcs[start + k + 2];
        unsigned int s3 = srcs[start + k + 3];
        float v0 = hs[(long long)s0 * 16 + f];
        float v1 = hs[(long long)s1 * 16 + f];
        float v2 = hs[(long long)s2 * 16 + f];
        float v3 = hs[(long long)s3 * 16 + f];
        acc += v0; acc += v1; acc += v2; acc += v3;
    }
    for (; k < cnt; ++k) acc += hs[(long long)srcs[start + k] * 16 + f];
    float v = dinv[g] * acc + b[f];
    float m = v;
#pragma unroll
    for (int o = 8; o >= 1; o >>= 1) m = fmaxf(m, __shfl_xor(m, o, 16));
    float ex = __expf(v - m);
#pragma unroll
    for (int o = 8; o >= 1; o >>= 1) ex += __shfl_xor(ex, o, 16);
    out[rb + f] = (v - m) - __logf(ex);
}

extern "C" void kernel_launch(void* const* d_in, const int* in_sizes, int n_in,
                              void* d_out, int out_size, void* d_ws, size_t ws_size,
                              hipStream_t stream) {
    const float* x  = (const float*)d_in[0];
    const void*  ei = d_in[1];
    const float* W1 = (const float*)d_in[2];
    const float* b1 = (const float*)d_in[3];
    const float* W2 = (const float*)d_in[4];
    const float* b2 = (const float*)d_in[5];

    long long dh  = in_sizes[3];                 // 64
    long long din = in_sizes[2] / dh;            // 64
    long long n   = in_sizes[0] / din;           // 50000
    long long E   = (long long)in_sizes[1] / 2;  // 1.6M
    int nbuckets  = (int)((n + BNODES - 1) >> BSHIFT);  // 782

    char* ws = (char*)d_ws;
    auto alloc = [&](size_t bytes) { void* p = ws; ws += (bytes + 255) & ~255ULL; return p; };
    int*   flag     = (int*)alloc(4);
    int*   totals   = (int*)alloc(nbuckets * 4);
    int*   base     = (int*)alloc(nbuckets * 4);
    int*   cursor   = (int*)alloc(nbuckets * 4);
    int*   rowstart = (int*)alloc(n * 4);
    int*   counts   = (int*)alloc(n * 4);
    float* dinv     = (float*)alloc(n * 4);
    unsigned int* keys = (unsigned int*)alloc(E * 4);
    unsigned short* h1b = (unsigned short*)alloc(n * 64 * 2);
    float* out1     = (float*)alloc(n * 64 * 4);
    float* h2s      = (float*)alloc(n * 16 * 4);
    // out1 is written only by gemm1-epoch kernels; before then its space
    // doubles as the (statistically never used) big-bucket sort scratch.
    unsigned int* sort_scratch = (unsigned int*)out1;

    float* out = (float*)d_out;

    hipMemsetAsync(totals, 0, (size_t)nbuckets * 4, stream);

    k_detect<<<1, 1, 0, stream>>>(ei, n, flag);
    k_buckcount<<<256, 512, 0, stream>>>(ei, flag, E, nbuckets, totals);
    k_scan<<<1, 1024, 0, stream>>>(totals, nbuckets, base, cursor);
    k_binscatter<<<256, 512, 0, stream>>>(ei, flag, E, nbuckets, cursor, keys);
    k_sortdeg<<<nbuckets, 256, 0, stream>>>(keys, base, totals, rowstart, counts,
                                            dinv, (int)n, sort_scratch);

    // layer 1
    k_gemm1<<<(int)(n / 16), 256, 0, stream>>>(x, W1, dinv, h1b);
    k_agg64<<<(int)((n * 64 + 255) / 256), 256, 0, stream>>>(
        rowstart, counts, keys, h1b, dinv, b1, out1, (int)n);

    // layer 2
    k_gemm2<<<(int)(n / 16), 256, 0, stream>>>(out1, W2, dinv, h2s);
    k_agg16<<<(int)((n * 16 + 255) / 256), 256, 0, stream>>>(
        rowstart, counts, keys, h2s, dinv, b2, out, (int)n);
}

// Round 8
// 134.258 us; speedup vs baseline: 6.9348x; 1.0787x over previous
//
#include <hip/hip_runtime.h>
#include <hip/hip_bf16.h>
#include <math.h>

// bucket = 64 consecutive dst nodes. key packs (dlow<<17 | src), valid for n < 131072.
#define BSHIFT 6
#define BNODES 64
#define MAXB 1024   // max buckets supported by single-block scan (n <= 65536)
#define SORTCAP 4096
#define TILE 16     // edges cached in registers per thread in k_binscatter

// ---------------- inline dtype detection: int64 vs int32 edge_index ----------------
__device__ __forceinline__ bool detect_f64(const void* edges, long long nn) {
    const long long* e64 = (const long long*)edges;
    bool ok = true;
#pragma unroll
    for (int i = 0; i < 8; ++i) {
        long long v = e64[i];
        ok = ok && (v >= 0 && v < nn);
    }
    return ok;
}

__device__ __forceinline__ float bf16lo(unsigned int u) {
    return __uint_as_float(u << 16);
}
__device__ __forceinline__ float bf16hi(unsigned int u) {
    return __uint_as_float(u & 0xFFFF0000u);
}
__device__ __forceinline__ float bf16dec(unsigned short u) {
    return __uint_as_float(((unsigned int)u) << 16);
}
__device__ __forceinline__ unsigned short bf16enc(float f) {
    __hip_bfloat16 h = __float2bfloat16(f);
    return *reinterpret_cast<unsigned short*>(&h);
}

// ---------------- per-bucket edge counts (LDS hist -> few global atomics) ----------------
__global__ __launch_bounds__(512) void k_buckcount(const void* edges, long long nn,
                                                   long long E, int nbuckets, int* totals) {
    __shared__ int cnt[MAXB];
    int t = threadIdx.x;
    for (int b = t; b < nbuckets; b += 512) cnt[b] = 0;
    __syncthreads();
    bool f64 = detect_f64(edges, nn);
    long long chunk = (E + gridDim.x - 1) / gridDim.x;
    long long e0 = (long long)blockIdx.x * chunk;
    long long e1 = e0 + chunk; if (e1 > E) e1 = E;
    for (long long e = e0 + t; e < e1; e += 512) {
        int d = f64 ? (int)((const long long*)edges)[E + e] : ((const int*)edges)[E + e];
        atomicAdd(&cnt[d >> BSHIFT], 1);
    }
    __syncthreads();
    for (int b = t; b < nbuckets; b += 512)
        if (cnt[b] > 0) atomicAdd(&totals[b], cnt[b]);
}

// ---------------- single-block scan: base = exclusive(totals), cursor = base ----------------
__global__ __launch_bounds__(1024) void k_scan(const int* __restrict__ totals, int nbuckets,
                                               int* base, int* cursor) {
    __shared__ int tmp[MAXB];
    int t = threadIdx.x;
    int v = (t < nbuckets) ? totals[t] : 0;
    tmp[t] = v;
    __syncthreads();
    for (int off = 1; off < MAXB; off <<= 1) {
        int a = (t >= off) ? tmp[t - off] : 0;
        __syncthreads();
        tmp[t] += a;
        __syncthreads();
    }
    if (t < nbuckets) {
        int ex = tmp[t] - v;
        base[t] = ex;
        cursor[t] = ex;
    }
}

// ------- bin edges into bucket-major key array (single edge read, reg-cached) -------
__global__ __launch_bounds__(512) void k_binscatter(const void* edges, long long nn,
                                                    long long E, int nbuckets, int* cursor,
                                                    unsigned int* keys) {
    __shared__ int cnt[MAXB];
    __shared__ int base_l[MAXB];
    int t = threadIdx.x;
    bool f64 = detect_f64(edges, nn);
    long long chunk = (E + gridDim.x - 1) / gridDim.x;
    long long e0 = (long long)blockIdx.x * chunk;
    long long e1 = e0 + chunk; if (e1 > E) e1 = E;
    for (long long tile0 = e0; tile0 < e1; tile0 += (long long)512 * TILE) {
        for (int b = t; b < nbuckets; b += 512) cnt[b] = 0;
        __syncthreads();
        int ss[TILE], dd[TILE];
        // pass 1: load once into registers + LDS histogram
#pragma unroll
        for (int j = 0; j < TILE; ++j) {
            long long e = tile0 + (long long)j * 512 + t;
            int s = 0, d = -1;
            if (e < e1) {
                if (f64) {
                    const long long* ee = (const long long*)edges;
                    s = (int)ee[e]; d = (int)ee[E + e];
                } else {
                    const int* ee = (const int*)edges;
                    s = ee[e]; d = ee[E + e];
                }
                atomicAdd(&cnt[d >> BSHIFT], 1);
            }
            ss[j] = s; dd[j] = d;
        }
        __syncthreads();
        // claim contiguous chunks per bucket
        for (int b = t; b < nbuckets; b += 512) {
            int c = cnt[b];
            base_l[b] = (c > 0) ? atomicAdd(&cursor[b], c) : 0;
            cnt[b] = 0;
        }
        __syncthreads();
        // pass 2: place keys from registers
#pragma unroll
        for (int j = 0; j < TILE; ++j) {
            int d = dd[j];
            if (d >= 0) {
                int b = d >> BSHIFT;
                int pos = base_l[b] + atomicAdd(&cnt[b], 1);
                keys[pos] = (unsigned int)ss[j] | ((unsigned int)(d & (BNODES - 1)) << 17);
            }
        }
        __syncthreads();
    }
}

// -------- per-bucket LDS counting sort -> node-exact CSR; fuses deg/dinv --------
__global__ __launch_bounds__(256) void k_sortdeg(unsigned int* keys,
                                                 const int* __restrict__ base,
                                                 const int* __restrict__ totals,
                                                 int* rowstart, int* counts,
                                                 float* dinv, int n,
                                                 unsigned int* scratch) {
    __shared__ unsigned int kbuf[SORTCAP];
    __shared__ int hist[BNODES];
    __shared__ int cur[BNODES];
    int t = threadIdx.x;
    int bk = blockIdx.x;
    int st = base[bk], c = totals[bk];
    if (t < BNODES) hist[t] = 0;
    __syncthreads();
    bool fits = (c <= SORTCAP);
    if (fits) {
        for (int i = t; i < c; i += 256) {
            unsigned int k = keys[st + i];
            kbuf[i] = k;
            atomicAdd(&hist[k >> 17], 1);
        }
    } else {  // statistically never for random edges; correct fallback via global scratch
        for (int i = t; i < c; i += 256) {
            unsigned int k = keys[st + i];
            scratch[st + i] = k;
            atomicAdd(&hist[k >> 17], 1);
        }
    }
    __syncthreads();
    if (t < 64) {  // wave 0: scan 64 counters
        int v = hist[t];
        int incl = v;
        for (int o = 1; o < 64; o <<= 1) {
            int other = __shfl_up(incl, o, 64);
            if (t >= o) incl += other;
        }
        int ex = incl - v;
        cur[t] = ex;
        int node = bk * BNODES + t;
        if (node < n) {
            rowstart[node] = st + ex;
            counts[node] = v;
            dinv[node] = rsqrtf((float)v + 1.0f);
        }
    }
    __syncthreads();
    if (fits) {
        for (int i = t; i < c; i += 256) {
            unsigned int k = kbuf[i];
            int pos = atomicAdd(&cur[k >> 17], 1);
            keys[st + pos] = k & 0x1FFFFu;
        }
    } else {
        for (int i = t; i < c; i += 256) {
            unsigned int k = scratch[st + i];
            int pos = atomicAdd(&cur[k >> 17], 1);
            keys[st + pos] = k & 0x1FFFFu;
        }
    }
}

// -------- GEMM1: h1b[n,64](bf16) = dinv * (x[n,64] @ W1[64,64]) --------
__global__ __launch_bounds__(256) void k_gemm1(const float* __restrict__ x,
                                               const float* __restrict__ W,
                                               const float* __restrict__ dinv,
                                               unsigned short* __restrict__ h) {
    __shared__ float Ws[64][64];
    __shared__ float xs[16][64];
    int t = threadIdx.x;
    for (int i = t; i < 64 * 64; i += 256) Ws[i >> 6][i & 63] = W[i];
    long long row0 = (long long)blockIdx.x * 16;
    ((float4*)xs)[t] = ((const float4*)(x + row0 * 64))[t];
    __syncthreads();
    int r = t >> 4, c0 = (t & 15) * 4;
    float4 acc = {0.f, 0.f, 0.f, 0.f};
#pragma unroll
    for (int k = 0; k < 64; ++k) {
        float xv = xs[r][k];
        float4 wv = *((const float4*)&Ws[k][c0]);
        acc.x += xv * wv.x; acc.y += xv * wv.y;
        acc.z += xv * wv.z; acc.w += xv * wv.w;
    }
    float di = dinv[row0 + r];
    ushort4 pk;
    pk.x = bf16enc(di * acc.x);
    pk.y = bf16enc(di * acc.y);
    pk.z = bf16enc(di * acc.z);
    pk.w = bf16enc(di * acc.w);
    *((ushort4*)(h + (row0 + r) * 64 + c0)) = pk;
}

// ------- GEMM2: h2b[n,16](bf16) = dinv * (out1b[n,64](bf16) @ W2[64,16]) -------
__global__ __launch_bounds__(256) void k_gemm2(const unsigned short* __restrict__ h,
                                               const float* __restrict__ W,
                                               const float* __restrict__ dinv,
                                               unsigned short* __restrict__ h2) {
    __shared__ float Ws[64 * 16];
    __shared__ float xs[16][64];
    int t = threadIdx.x;
    for (int i = t; i < 64 * 16; i += 256) Ws[i] = W[i];
    long long row0 = (long long)blockIdx.x * 16;
    ushort4 u4 = ((const ushort4*)(h + row0 * 64))[t];
    int lr = t >> 4, lc = (t & 15) * 4;
    xs[lr][lc + 0] = bf16dec(u4.x);
    xs[lr][lc + 1] = bf16dec(u4.y);
    xs[lr][lc + 2] = bf16dec(u4.z);
    xs[lr][lc + 3] = bf16dec(u4.w);
    __syncthreads();
    int r = t >> 4, c = t & 15;
    float acc = 0.f;
#pragma unroll
    for (int k = 0; k < 64; ++k) acc += xs[r][k] * Ws[k * 16 + c];
    h2[(row0 + r) * 16 + c] = bf16enc(dinv[row0 + r] * acc);
}

// ------- CSR aggregation, 64 feats (bf16 h, 2-wide): wave per node --------------
// 32 lanes cover a 128B row (uint = 2 bf16 feats); half-waves take even/odd edges.
__global__ __launch_bounds__(256) void k_agg64(const int* __restrict__ rowstart,
                                               const int* __restrict__ counts,
                                               const unsigned int* __restrict__ srcs,
                                               const unsigned int* __restrict__ hb2,
                                               const float* __restrict__ dinv,
                                               const float* __restrict__ b,
                                               unsigned short* __restrict__ out, int n) {
    int d = (blockIdx.x * 256 + threadIdx.x) >> 6;
    if (d >= n) return;
    int lane = threadIdx.x & 63;
    int half = lane >> 5;     // 0: even edges, 1: odd edges
    int fl = lane & 31;       // feature-pair index (features 2fl, 2fl+1)
    float ax = 0.f, ay = 0.f;
    if (half == 0) {          // self-loop counted once
        unsigned int u = hb2[(long long)d * 32 + fl];
        ax = bf16lo(u); ay = bf16hi(u);
    }
    int start = rowstart[d];
    int cnt = counts[d];
    int k = 0;
    for (; k + 8 <= cnt; k += 8) {
        unsigned int s0 = srcs[start + k + half];
        unsigned int s1 = srcs[start + k + 2 + half];
        unsigned int s2 = srcs[start + k + 4 + half];
        unsigned int s3 = srcs[start + k + 6 + half];
        unsigned int u0 = hb2[(long long)s0 * 32 + fl];
        unsigned int u1 = hb2[(long long)s1 * 32 + fl];
        unsigned int u2 = hb2[(long long)s2 * 32 + fl];
        unsigned int u3 = hb2[(long long)s3 * 32 + fl];
        ax += bf16lo(u0); ay += bf16hi(u0);
        ax += bf16lo(u1); ay += bf16hi(u1);
        ax += bf16lo(u2); ay += bf16hi(u2);
        ax += bf16lo(u3); ay += bf16hi(u3);
    }
    for (; k < cnt; k += 2) {
        int idx = k + half;
        unsigned int u0 = 0;
        if (idx < cnt) u0 = hb2[(long long)srcs[start + idx] * 32 + fl];
        ax += bf16lo(u0); ay += bf16hi(u0);
    }
    // combine even/odd halves (lane <-> lane^32 holds same fl)
    ax += __shfl_xor(ax, 32);
    ay += __shfl_xor(ay, 32);
    float di = dinv[d];
    float2 bb = ((const float2*)b)[fl];
    float ox = fmaxf(di * ax + bb.x, 0.f);
    float oy = fmaxf(di * ay + bb.y, 0.f);
    if (half == 0) {
        unsigned int pk = (unsigned int)bf16enc(ox) | ((unsigned int)bf16enc(oy) << 16);
        ((unsigned int*)(out + (long long)d * 64))[fl] = pk;
    }
}

// ------- CSR aggregation, 16 feats (bf16 h) + fused log_softmax ----------------
__global__ __launch_bounds__(256) void k_agg16(const int* __restrict__ rowstart,
                                               const int* __restrict__ counts,
                                               const unsigned int* __restrict__ srcs,
                                               const unsigned short* __restrict__ hb,
                                               const float* __restrict__ dinv,
                                               const float* __restrict__ b,
                                               float* __restrict__ out, int n) {
    int g = (blockIdx.x * 256 + threadIdx.x) >> 4;
    if (g >= n) return;
    int f = threadIdx.x & 15;
    long long rb = (long long)g * 16;
    float acc = bf16dec(hb[rb + f]);
    int start = rowstart[g];
    int cnt = counts[g];
    int k = 0;
    for (; k + 8 <= cnt; k += 8) {
        unsigned int s0 = srcs[start + k];
        unsigned int s1 = srcs[start + k + 1];
        unsigned int s2 = srcs[start + k + 2];
        unsigned int s3 = srcs[start + k + 3];
        unsigned int s4 = srcs[start + k + 4];
        unsigned int s5 = srcs[start + k + 5];
        unsigned int s6 = srcs[start + k + 6];
        unsigned int s7 = srcs[start + k + 7];
        unsigned short u0 = hb[(long long)s0 * 16 + f];
        unsigned short u1 = hb[(long long)s1 * 16 + f];
        unsigned short u2 = hb[(long long)s2 * 16 + f];
        unsigned short u3 = hb[(long long)s3 * 16 + f];
        unsigned short u4 = hb[(long long)s4 * 16 + f];
        unsigned short u5 = hb[(long long)s5 * 16 + f];
        unsigned short u6 = hb[(long long)s6 * 16 + f];
        unsigned short u7 = hb[(long long)s7 * 16 + f];
        acc += bf16dec(u0); acc += bf16dec(u1); acc += bf16dec(u2); acc += bf16dec(u3);
        acc += bf16dec(u4); acc += bf16dec(u5); acc += bf16dec(u6); acc += bf16dec(u7);
    }
    for (; k < cnt; ++k) acc += bf16dec(hb[(long long)srcs[start + k] * 16 + f]);
    float v = dinv[g] * acc + b[f];
    float m = v;
#pragma unroll
    for (int o = 8; o >= 1; o >>= 1) m = fmaxf(m, __shfl_xor(m, o, 16));
    float ex = __expf(v - m);
#pragma unroll
    for (int o = 8; o >= 1; o >>= 1) ex += __shfl_xor(ex, o, 16);
    out[rb + f] = (v - m) - __logf(ex);
}

extern "C" void kernel_launch(void* const* d_in, const int* in_sizes, int n_in,
                              void* d_out, int out_size, void* d_ws, size_t ws_size,
                              hipStream_t stream) {
    const float* x  = (const float*)d_in[0];
    const void*  ei = d_in[1];
    const float* W1 = (const float*)d_in[2];
    const float* b1 = (const float*)d_in[3];
    const float* W2 = (const float*)d_in[4];
    const float* b2 = (const float*)d_in[5];

    long long dh  = in_sizes[3];                 // 64
    long long din = in_sizes[2] / dh;            // 64
    long long n   = in_sizes[0] / din;           // 50000
    long long E   = (long long)in_sizes[1] / 2;  // 1.6M
    int nbuckets  = (int)((n + BNODES - 1) >> BSHIFT);  // 782

    char* ws = (char*)d_ws;
    auto alloc = [&](size_t bytes) { void* p = ws; ws += (bytes + 255) & ~255ULL; return p; };
    int*   totals   = (int*)alloc(nbuckets * 4);
    int*   base     = (int*)alloc(nbuckets * 4);
    int*   cursor   = (int*)alloc(nbuckets * 4);
    int*   rowstart = (int*)alloc(n * 4);
    int*   counts   = (int*)alloc(n * 4);
    float* dinv     = (float*)alloc(n * 4);
    unsigned int* keys = (unsigned int*)alloc(E * 4);
    unsigned short* h1b  = (unsigned short*)alloc(n * 64 * 2);
    unsigned short* out1 = (unsigned short*)alloc(n * 64 * 2);
    unsigned short* h2b  = (unsigned short*)alloc(n * 16 * 2);
    // out1 written only after sortdeg completes; before then its space doubles
    // as the (statistically never used) big-bucket sort scratch (needs E*4 <= n*64*2).
    unsigned int* sort_scratch = (unsigned int*)out1;

    float* out = (float*)d_out;

    hipMemsetAsync(totals, 0, (size_t)nbuckets * 4, stream);

    k_buckcount<<<256, 512, 0, stream>>>(ei, n, E, nbuckets, totals);
    k_scan<<<1, 1024, 0, stream>>>(totals, nbuckets, base, cursor);
    k_binscatter<<<256, 512, 0, stream>>>(ei, n, E, nbuckets, cursor, keys);
    k_sortdeg<<<nbuckets, 256, 0, stream>>>(keys, base, totals, rowstart, counts,
                                            dinv, (int)n, sort_scratch);

    // layer 1
    k_gemm1<<<(int)(n / 16), 256, 0, stream>>>(x, W1, dinv, h1b);
    k_agg64<<<(int)((n * 64 + 255) / 256), 256, 0, stream>>>(
        rowstart, counts, keys, (const unsigned int*)h1b, dinv, b1, out1, (int)n);

    // layer 2
    k_gemm2<<<(int)(n / 16), 256, 0, stream>>>(out1, W2, dinv, h2b);
    k_agg16<<<(int)((n * 16 + 255) / 256), 256, 0, stream>>>(
        rowstart, counts, keys, h2b, dinv, b2, out, (int)n);
}